// Round 1
// baseline (2663.395 us; speedup 1.0000x reference)
//
#include <hip/hip_runtime.h>
#include <math.h>

// Problem constants (D=128, T=4, R=4, H=8, DK=16 are structural; N,E passed in)
#define D_DIM 128

__device__ __forceinline__ unsigned enc_f32(float x) {
    unsigned b = __float_as_uint(x);
    return (b & 0x80000000u) ? ~b : (b | 0x80000000u);
}
__device__ __forceinline__ float dec_f32(unsigned k) {
    unsigned b = (k & 0x80000000u) ? (k ^ 0x80000000u) : ~k;
    return __uint_as_float(b);
}

// ---------------- type sort (counting sort, T=4) ----------------
__global__ void hist_k(const int* __restrict__ nt, int* __restrict__ cnt, int N) {
    int i = blockIdx.x * 256 + threadIdx.x;
    if (i < N) atomicAdd(&cnt[nt[i]], 1);
}
__global__ void scan_k(const int* __restrict__ cnt, int* __restrict__ cursor) {
    if (threadIdx.x == 0) {
        int s = 0;
        for (int t = 0; t < 4; ++t) { cursor[t] = s; s += cnt[t]; }
    }
}
__global__ void scatter_k(const int* __restrict__ nt, int* __restrict__ cursor,
                          int* __restrict__ order, int N) {
    int i = blockIdx.x * 256 + threadIdx.x;
    if (i < N) {
        int p = atomicAdd(&cursor[nt[i]], 1);
        order[p] = i;
    }
}

// ---------------- K/Q/V projections: 16 nodes per 128-thread block ----------------
__global__ __launch_bounds__(128)
void proj_kqv(const float* __restrict__ x, const int* __restrict__ nt,
              const int* __restrict__ order,
              const float* __restrict__ Wk, const float* __restrict__ bk,
              const float* __restrict__ Wq, const float* __restrict__ bq,
              const float* __restrict__ Wv, const float* __restrict__ bv,
              float* __restrict__ K, float* __restrict__ Q, float* __restrict__ V,
              int N) {
    __shared__ float xs[16][128];
    __shared__ int gid_s[16], typ_s[16];
    int o = threadIdx.x;
    int base = blockIdx.x * 16;
    if (o < 16) {
        int n = base + o;
        int g = (n < N) ? order[n] : -1;
        gid_s[o] = g;
        typ_s[o] = (g >= 0) ? nt[g] : 0;
    }
    __syncthreads();
    for (int n = 0; n < 16; ++n) {
        int g = gid_s[n];
        xs[n][o] = (g >= 0) ? x[(size_t)g * D_DIM + o] : 0.f;
    }
    __syncthreads();

    int t0 = typ_s[0];
    bool uniform = true;
    for (int n = 1; n < 16; ++n) uniform &= (typ_s[n] == t0);

    float ak[16], aq[16], av[16];
    if (uniform) {
        float bkv = bk[t0 * 128 + o], bqv = bq[t0 * 128 + o], bvv = bv[t0 * 128 + o];
        for (int n = 0; n < 16; ++n) { ak[n] = bkv; aq[n] = bqv; av[n] = bvv; }
        const float* wkp = Wk + (size_t)t0 * 16384 + o;
        const float* wqp = Wq + (size_t)t0 * 16384 + o;
        const float* wvp = Wv + (size_t)t0 * 16384 + o;
        #pragma unroll 4
        for (int i = 0; i < 128; ++i) {
            float wk = wkp[i * 128], wq = wqp[i * 128], wv = wvp[i * 128];
            #pragma unroll
            for (int n = 0; n < 16; ++n) {
                float xv = xs[n][i];
                ak[n] = fmaf(xv, wk, ak[n]);
                aq[n] = fmaf(xv, wq, aq[n]);
                av[n] = fmaf(xv, wv, av[n]);
            }
        }
    } else {
        for (int n = 0; n < 16; ++n) {
            int t = typ_s[n];
            ak[n] = bk[t * 128 + o]; aq[n] = bq[t * 128 + o]; av[n] = bv[t * 128 + o];
        }
        for (int i = 0; i < 128; ++i) {
            #pragma unroll
            for (int n = 0; n < 16; ++n) {
                int t = typ_s[n];
                float xv = xs[n][i];
                ak[n] = fmaf(xv, Wk[(size_t)t * 16384 + i * 128 + o], ak[n]);
                aq[n] = fmaf(xv, Wq[(size_t)t * 16384 + i * 128 + o], aq[n]);
                av[n] = fmaf(xv, Wv[(size_t)t * 16384 + i * 128 + o], av[n]);
            }
        }
    }
    for (int n = 0; n < 16; ++n) {
        int g = gid_s[n];
        if (g >= 0) {
            K[(size_t)g * D_DIM + o] = ak[n];
            Q[(size_t)g * D_DIM + o] = aq[n];
            V[(size_t)g * D_DIM + o] = av[n];
        }
    }
}

// ---------------- edge logits + segment max: one wave per edge ----------------
__global__ __launch_bounds__(256)
void edge_logits(const float* __restrict__ K, const float* __restrict__ Q,
                 const int* __restrict__ ei, const int* __restrict__ et,
                 const float* __restrict__ rel_att, const float* __restrict__ rel_pri,
                 float* __restrict__ logit, unsigned* __restrict__ segmax, int E) {
    __shared__ float sk[4][128];
    __shared__ float sq[4][128];
    int w = threadIdx.x >> 6;
    int l = threadIdx.x & 63;
    int e = blockIdx.x * 4 + w;
    bool act = (e < E);
    int src = 0, dst = 0, r = 0;
    if (act) {
        src = ei[e]; dst = ei[E + e]; r = et[e];
        sk[w][l]      = K[(size_t)src * 128 + l];
        sk[w][l + 64] = K[(size_t)src * 128 + 64 + l];
        sq[w][l]      = Q[(size_t)dst * 128 + l];
        sq[w][l + 64] = Q[(size_t)dst * 128 + 64 + l];
    }
    __syncthreads();
    if (act) {
        int h = l >> 3;
        int c0 = (l & 7) * 2, c1 = c0 + 1;
        const float* ra = rel_att + ((size_t)(r * 8 + h)) * 256;
        float a0 = 0.f, a1 = 0.f;
        #pragma unroll
        for (int d = 0; d < 16; ++d) {
            float kv = sk[w][h * 16 + d];
            a0 = fmaf(kv, ra[d * 16 + c0], a0);
            a1 = fmaf(kv, ra[d * 16 + c1], a1);
        }
        float p = sq[w][h * 16 + c0] * a0 + sq[w][h * 16 + c1] * a1;
        p += __shfl_xor(p, 1);
        p += __shfl_xor(p, 2);
        p += __shfl_xor(p, 4);
        if ((l & 7) == 0) {
            float lg = p * rel_pri[r * 8 + h] * 0.25f;  // 1/sqrt(16)
            logit[(size_t)e * 8 + h] = lg;
            atomicMax(&segmax[(size_t)dst * 8 + h], enc_f32(lg));
        }
    }
}

// ---------------- exp + denom ----------------
__global__ __launch_bounds__(256)
void edge_exp(float* __restrict__ logit, const int* __restrict__ ei,
              const unsigned* __restrict__ segmax, float* __restrict__ denom, int E) {
    long long idx = (long long)blockIdx.x * 256 + threadIdx.x;
    if (idx >= (long long)E * 8) return;
    int e = (int)(idx >> 3), h = (int)(idx & 7);
    int dst = ei[E + e];
    float m = dec_f32(segmax[(size_t)dst * 8 + h]);
    float ex = expf(logit[idx] - m);
    logit[idx] = ex;
    atomicAdd(&denom[(size_t)dst * 8 + h], ex);
}

// ---------------- message + weighted aggregation: one wave per edge ----------------
__global__ __launch_bounds__(256)
void edge_aggr(const float* __restrict__ V, const int* __restrict__ ei,
               const int* __restrict__ et, const float* __restrict__ rel_msg,
               const float* __restrict__ ex, const float* __restrict__ denom,
               float* __restrict__ aggr, int E) {
    __shared__ float sv[4][128];
    int w = threadIdx.x >> 6;
    int l = threadIdx.x & 63;
    int e = blockIdx.x * 4 + w;
    bool act = (e < E);
    int src = 0, dst = 0, r = 0;
    if (act) {
        src = ei[e]; dst = ei[E + e]; r = et[e];
        sv[w][l]      = V[(size_t)src * 128 + l];
        sv[w][l + 64] = V[(size_t)src * 128 + 64 + l];
    }
    __syncthreads();
    if (act) {
        int h = l >> 3;
        int c0 = (l & 7) * 2, c1 = c0 + 1;
        const float* rm = rel_msg + ((size_t)(r * 8 + h)) * 256;
        float a0 = 0.f, a1 = 0.f;
        #pragma unroll
        for (int d = 0; d < 16; ++d) {
            float vv = sv[w][h * 16 + d];
            a0 = fmaf(vv, rm[d * 16 + c0], a0);
            a1 = fmaf(vv, rm[d * 16 + c1], a1);
        }
        float att = ex[(size_t)e * 8 + h] / denom[(size_t)dst * 8 + h];
        atomicAdd(&aggr[(size_t)dst * 128 + h * 16 + c0], att * a0);
        atomicAdd(&aggr[(size_t)dst * 128 + h * 16 + c1], att * a1);
    }
}

// ---------------- gelu + Wa proj + skip + LayerNorm ----------------
__global__ __launch_bounds__(128)
void node_out(const float* __restrict__ aggr, const float* __restrict__ x,
              const int* __restrict__ nt, const int* __restrict__ order,
              const float* __restrict__ Wa, const float* __restrict__ ba,
              const float* __restrict__ skip, const float* __restrict__ gamma,
              const float* __restrict__ beta, float* __restrict__ out, int N) {
    __shared__ float hs[16][132];
    __shared__ int gid_s[16], typ_s[16];
    __shared__ float mu_s[16], rs_s[16];
    int o = threadIdx.x;
    int base = blockIdx.x * 16;
    if (o < 16) {
        int n = base + o;
        int g = (n < N) ? order[n] : -1;
        gid_s[o] = g;
        typ_s[o] = (g >= 0) ? nt[g] : 0;
    }
    __syncthreads();
    for (int n = 0; n < 16; ++n) {
        int g = gid_s[n];
        float v = (g >= 0) ? aggr[(size_t)g * 128 + o] : 0.f;
        hs[n][o] = 0.5f * v * (1.f + erff(v * 0.70710678118654752f));  // exact gelu
    }
    __syncthreads();

    int t0 = typ_s[0];
    bool uniform = true;
    for (int n = 1; n < 16; ++n) uniform &= (typ_s[n] == t0);

    float acc[16];
    if (uniform) {
        float bv = ba[t0 * 128 + o];
        for (int n = 0; n < 16; ++n) acc[n] = bv;
        const float* wp = Wa + (size_t)t0 * 16384 + o;
        #pragma unroll 4
        for (int i = 0; i < 128; ++i) {
            float wv = wp[i * 128];
            #pragma unroll
            for (int n = 0; n < 16; ++n) acc[n] = fmaf(hs[n][i], wv, acc[n]);
        }
    } else {
        for (int n = 0; n < 16; ++n) acc[n] = ba[typ_s[n] * 128 + o];
        for (int i = 0; i < 128; ++i) {
            #pragma unroll
            for (int n = 0; n < 16; ++n)
                acc[n] = fmaf(hs[n][i], Wa[(size_t)typ_s[n] * 16384 + i * 128 + o], acc[n]);
        }
    }
    __syncthreads();  // done reading hs (gelu values); reuse for pre

    float pre[16];
    for (int n = 0; n < 16; ++n) {
        int g = gid_s[n];
        if (g >= 0) {
            float al = 1.f / (1.f + expf(-skip[typ_s[n]]));
            pre[n] = acc[n] * al + x[(size_t)g * 128 + o] * (1.f - al);
        } else pre[n] = 0.f;
        hs[n][o] = pre[n];
    }
    __syncthreads();

    // per-node mean/var: 8 threads per node
    int rn = o >> 3, j = o & 7;
    float s = 0.f, sq = 0.f;
    #pragma unroll
    for (int k2 = 0; k2 < 16; ++k2) {
        float v = hs[rn][j + 8 * k2];
        s += v; sq += v * v;
    }
    s += __shfl_xor(s, 1); sq += __shfl_xor(sq, 1);
    s += __shfl_xor(s, 2); sq += __shfl_xor(sq, 2);
    s += __shfl_xor(s, 4); sq += __shfl_xor(sq, 4);
    if (j == 0) {
        float mu = s * (1.f / 128.f);
        float var = sq * (1.f / 128.f) - mu * mu;
        mu_s[rn] = mu;
        rs_s[rn] = rsqrtf(fmaxf(var, 0.f) + 1e-5f);
    }
    __syncthreads();

    for (int n = 0; n < 16; ++n) {
        int g = gid_s[n];
        if (g >= 0) {
            int t = typ_s[n];
            out[(size_t)g * 128 + o] =
                (pre[n] - mu_s[n]) * rs_s[n] * gamma[t * 128 + o] + beta[t * 128 + o];
        }
    }
}

extern "C" void kernel_launch(void* const* d_in, const int* in_sizes, int n_in,
                              void* d_out, int out_size, void* d_ws, size_t ws_size,
                              hipStream_t stream) {
    const float* x   = (const float*)d_in[0];
    const int*   nt  = (const int*)d_in[1];
    const int*   ei  = (const int*)d_in[2];
    const int*   et  = (const int*)d_in[3];
    // d_in[4] edge_spatial: unused by reference
    const float* Wk = (const float*)d_in[5];  const float* bk = (const float*)d_in[6];
    const float* Wq = (const float*)d_in[7];  const float* bq = (const float*)d_in[8];
    const float* Wv = (const float*)d_in[9];  const float* bv = (const float*)d_in[10];
    const float* Wa = (const float*)d_in[11]; const float* ba = (const float*)d_in[12];
    const float* rel_pri = (const float*)d_in[13];
    const float* rel_att = (const float*)d_in[14];
    const float* rel_msg = (const float*)d_in[15];
    const float* skip    = (const float*)d_in[16];
    const float* gamma   = (const float*)d_in[17];
    const float* beta    = (const float*)d_in[18];

    const int N = in_sizes[0] / 128;
    const int E = in_sizes[3];

    float* ws = (float*)d_ws;
    float* Kb = ws;
    float* Qb = Kb + (size_t)N * 128;
    float* Vb = Qb + (size_t)N * 128;
    float* logit = Vb + (size_t)N * 128;            // E*8, reused as ex
    unsigned* segmax = (unsigned*)(logit + (size_t)E * 8);  // N*8
    float* denom = (float*)(segmax + (size_t)N * 8);        // N*8
    float* aggr  = denom + (size_t)N * 8;                   // N*128
    int* order   = (int*)(aggr + (size_t)N * 128);          // N
    int* cnt     = order + N;                               // 4
    int* cursor  = cnt + 4;                                 // 4

    hipMemsetAsync(segmax, 0, (size_t)N * 8 * sizeof(unsigned), stream);
    hipMemsetAsync(denom, 0, (size_t)N * 8 * sizeof(float), stream);
    hipMemsetAsync(aggr, 0, (size_t)N * 128 * sizeof(float), stream);
    hipMemsetAsync(cnt, 0, 8 * sizeof(int), stream);

    hist_k<<<(N + 255) / 256, 256, 0, stream>>>(nt, cnt, N);
    scan_k<<<1, 64, 0, stream>>>(cnt, cursor);
    scatter_k<<<(N + 255) / 256, 256, 0, stream>>>(nt, cursor, order, N);

    int nb = (N + 15) / 16;
    proj_kqv<<<nb, 128, 0, stream>>>(x, nt, order, Wk, bk, Wq, bq, Wv, bv, Kb, Qb, Vb, N);
    edge_logits<<<(E + 3) / 4, 256, 0, stream>>>(Kb, Qb, ei, et, rel_att, rel_pri,
                                                 logit, segmax, E);
    edge_exp<<<(int)(((long long)E * 8 + 255) / 256), 256, 0, stream>>>(logit, ei, segmax,
                                                                        denom, E);
    edge_aggr<<<(E + 3) / 4, 256, 0, stream>>>(Vb, ei, et, rel_msg, logit, denom, aggr, E);
    node_out<<<nb, 128, 0, stream>>>(aggr, x, nt, order, Wa, ba, skip, gamma, beta,
                                     (float*)d_out, N);
}

// Round 2
// 2278.426 us; speedup vs baseline: 1.1690x; 1.1690x over previous
//
#include <hip/hip_runtime.h>
#include <math.h>

#define D_DIM 128

// ---------------- type sort (counting sort, T=4) ----------------
__global__ void hist_k(const int* __restrict__ nt, int* __restrict__ cnt, int N) {
    int i = blockIdx.x * 256 + threadIdx.x;
    if (i < N) atomicAdd(&cnt[nt[i]], 1);
}
__global__ void scan_types_k(const int* __restrict__ cnt, int* __restrict__ cursor) {
    if (threadIdx.x == 0) {
        int s = 0;
        for (int t = 0; t < 4; ++t) { cursor[t] = s; s += cnt[t]; }
    }
}
__global__ void scatter_types_k(const int* __restrict__ nt, int* __restrict__ cursor,
                                int* __restrict__ order, int N) {
    int i = blockIdx.x * 256 + threadIdx.x;
    if (i < N) {
        int p = atomicAdd(&cursor[nt[i]], 1);
        order[p] = i;
    }
}

// ---------------- dst-CSR build ----------------
__global__ void deg_k(const int* __restrict__ ei, int* __restrict__ deg, int E) {
    int e = blockIdx.x * 256 + threadIdx.x;
    if (e < E) atomicAdd(&deg[ei[E + e]], 1);
}
__global__ void scan1_k(const int* __restrict__ deg, int* __restrict__ excl,
                        int* __restrict__ bsum, int N) {
    __shared__ int s[512];
    int i = blockIdx.x * 512 + threadIdx.x;
    int v = (i < N) ? deg[i] : 0;
    s[threadIdx.x] = v;
    __syncthreads();
    for (int off = 1; off < 512; off <<= 1) {
        int t = (threadIdx.x >= off) ? s[threadIdx.x - off] : 0;
        __syncthreads();
        s[threadIdx.x] += t;
        __syncthreads();
    }
    if (i < N) excl[i] = s[threadIdx.x] - v;
    if (threadIdx.x == 511) bsum[blockIdx.x] = s[511];
}
__global__ void scan2_k(int* __restrict__ bsum, int nb) {
    if (threadIdx.x == 0) {
        int run = 0;
        for (int b = 0; b < nb; ++b) { int t = bsum[b]; bsum[b] = run; run += t; }
    }
}
__global__ void scan3_k(int* __restrict__ excl, const int* __restrict__ bsum, int N) {
    int i = blockIdx.x * 512 + threadIdx.x;
    if (i < N) excl[i] += bsum[blockIdx.x];
}
__global__ void scatter_edges_k(const int* __restrict__ ei, const int* __restrict__ et,
                                const int* __restrict__ off, int* __restrict__ cursor,
                                int* __restrict__ elist, int E) {
    int e = blockIdx.x * 256 + threadIdx.x;
    if (e < E) {
        int dst = ei[E + e];
        int p = off[dst] + atomicAdd(&cursor[dst], 1);
        elist[p] = (ei[e] << 2) | et[e];
    }
}

// ---------------- K/Q/V projections: 16 nodes per 128-thread block ----------------
__global__ __launch_bounds__(128)
void proj_kqv(const float* __restrict__ x, const int* __restrict__ nt,
              const int* __restrict__ order,
              const float* __restrict__ Wk, const float* __restrict__ bk,
              const float* __restrict__ Wq, const float* __restrict__ bq,
              const float* __restrict__ Wv, const float* __restrict__ bv,
              float* __restrict__ K, float* __restrict__ Q, float* __restrict__ V,
              int N) {
    __shared__ float xs[16][128];
    __shared__ int gid_s[16], typ_s[16];
    int o = threadIdx.x;
    int base = blockIdx.x * 16;
    if (o < 16) {
        int n = base + o;
        int g = (n < N) ? order[n] : -1;
        gid_s[o] = g;
        typ_s[o] = (g >= 0) ? nt[g] : 0;
    }
    __syncthreads();
    for (int n = 0; n < 16; ++n) {
        int g = gid_s[n];
        xs[n][o] = (g >= 0) ? x[(size_t)g * D_DIM + o] : 0.f;
    }
    __syncthreads();

    int t0 = typ_s[0];
    bool uniform = true;
    for (int n = 1; n < 16; ++n) uniform &= (typ_s[n] == t0);

    float ak[16], aq[16], av[16];
    if (uniform) {
        float bkv = bk[t0 * 128 + o], bqv = bq[t0 * 128 + o], bvv = bv[t0 * 128 + o];
        for (int n = 0; n < 16; ++n) { ak[n] = bkv; aq[n] = bqv; av[n] = bvv; }
        const float* wkp = Wk + (size_t)t0 * 16384 + o;
        const float* wqp = Wq + (size_t)t0 * 16384 + o;
        const float* wvp = Wv + (size_t)t0 * 16384 + o;
        #pragma unroll 4
        for (int i = 0; i < 128; ++i) {
            float wk = wkp[i * 128], wq = wqp[i * 128], wv = wvp[i * 128];
            #pragma unroll
            for (int n = 0; n < 16; ++n) {
                float xv = xs[n][i];
                ak[n] = fmaf(xv, wk, ak[n]);
                aq[n] = fmaf(xv, wq, aq[n]);
                av[n] = fmaf(xv, wv, av[n]);
            }
        }
    } else {
        for (int n = 0; n < 16; ++n) {
            int t = typ_s[n];
            ak[n] = bk[t * 128 + o]; aq[n] = bq[t * 128 + o]; av[n] = bv[t * 128 + o];
        }
        for (int i = 0; i < 128; ++i) {
            #pragma unroll
            for (int n = 0; n < 16; ++n) {
                int t = typ_s[n];
                float xv = xs[n][i];
                ak[n] = fmaf(xv, Wk[(size_t)t * 16384 + i * 128 + o], ak[n]);
                aq[n] = fmaf(xv, Wq[(size_t)t * 16384 + i * 128 + o], aq[n]);
                av[n] = fmaf(xv, Wv[(size_t)t * 16384 + i * 128 + o], av[n]);
            }
        }
    }
    for (int n = 0; n < 16; ++n) {
        int g = gid_s[n];
        if (g >= 0) {
            K[(size_t)g * D_DIM + o] = ak[n];
            Q[(size_t)g * D_DIM + o] = aq[n];
            V[(size_t)g * D_DIM + o] = av[n];
        }
    }
}

// ---------------- fused per-dst edge kernel: one wave per dst ----------------
// lane l: head h = l>>3, dims d0 = (l&7)*2, d0+1
__global__ __launch_bounds__(256)
void edge_fused(const float* __restrict__ K, const float* __restrict__ Q,
                const float* __restrict__ V,
                const int* __restrict__ off, const int* __restrict__ elist,
                const float* __restrict__ rel_att, const float* __restrict__ rel_msg,
                const float* __restrict__ rel_pri,
                float* __restrict__ aggr, int N, int E) {
    __shared__ float sq[4][128];
    __shared__ float Ssh[4][512];  // [wave][r*128 + h*16 + d]
    int w = threadIdx.x >> 6, l = threadIdx.x & 63;
    int dst = blockIdx.x * 4 + w;
    bool act = (dst < N);
    int h = l >> 3;
    int d0 = (l & 7) * 2;

    if (act) {
        float2 qv = *(const float2*)&Q[(size_t)dst * 128 + 2 * l];
        sq[w][2 * l] = qv.x;
        sq[w][2 * l + 1] = qv.y;
    }
    __syncthreads();

    // qrel[r][d0],[d0+1] in registers (all static indexing)
    float qr[4][2];
    float pr[4];
    if (act) {
        #pragma unroll
        for (int r = 0; r < 4; ++r) {
            float a0 = 0.f, a1 = 0.f;
            const float* ra = rel_att + ((size_t)(r * 8 + h)) * 256 + d0 * 16;
            #pragma unroll
            for (int k = 0; k < 16; ++k) {
                float qv = sq[w][h * 16 + k];
                a0 = fmaf(qv, ra[k], a0);
                a1 = fmaf(qv, ra[16 + k], a1);
            }
            qr[r][0] = a0; qr[r][1] = a1;
            pr[r] = rel_pri[r * 8 + h] * 0.25f;  // 1/sqrt(DK)
        }
    } else {
        #pragma unroll
        for (int r = 0; r < 4; ++r) { qr[r][0] = qr[r][1] = 0.f; pr[r] = 0.f; }
    }

    float S[4][2];
    #pragma unroll
    for (int r = 0; r < 4; ++r) { S[r][0] = 0.f; S[r][1] = 0.f; }
    float den = 0.f;

    int e0 = act ? off[dst] : 0;
    int e1 = 0;
    if (act) e1 = (dst == N - 1) ? E : off[dst + 1];

    for (int p = e0; p < e1; ++p) {
        int pk = elist[p];  // wave-uniform
        int src = pk >> 2;
        int rs = __builtin_amdgcn_readfirstlane(pk & 3);
        float2 kv = *(const float2*)&K[(size_t)src * 128 + 2 * l];
        float2 vv = *(const float2*)&V[(size_t)src * 128 + 2 * l];
        float a, b, pri;
        if (rs == 0)      { a = qr[0][0]; b = qr[0][1]; pri = pr[0]; }
        else if (rs == 1) { a = qr[1][0]; b = qr[1][1]; pri = pr[1]; }
        else if (rs == 2) { a = qr[2][0]; b = qr[2][1]; pri = pr[2]; }
        else              { a = qr[3][0]; b = qr[3][1]; pri = pr[3]; }
        float dt = kv.x * a + kv.y * b;
        dt += __shfl_xor(dt, 1);
        dt += __shfl_xor(dt, 2);
        dt += __shfl_xor(dt, 4);
        float wgt = expf(dt * pri);  // no max-subtraction: |logit| small, ratio identical
        den += wgt;
        if (rs == 0)      { S[0][0] = fmaf(wgt, vv.x, S[0][0]); S[0][1] = fmaf(wgt, vv.y, S[0][1]); }
        else if (rs == 1) { S[1][0] = fmaf(wgt, vv.x, S[1][0]); S[1][1] = fmaf(wgt, vv.y, S[1][1]); }
        else if (rs == 2) { S[2][0] = fmaf(wgt, vv.x, S[2][0]); S[2][1] = fmaf(wgt, vv.y, S[2][1]); }
        else              { S[3][0] = fmaf(wgt, vv.x, S[3][0]); S[3][1] = fmaf(wgt, vv.y, S[3][1]); }
    }

    // dump S to LDS for cross-lane transform
    #pragma unroll
    for (int r = 0; r < 4; ++r) {
        Ssh[w][r * 128 + 2 * l] = S[r][0];
        Ssh[w][r * 128 + 2 * l + 1] = S[r][1];
    }
    __syncthreads();  // every thread reaches (loop lengths differ but all arrive)

    if (act) {
        // aggr[h,k0..k0+1] = (1/den) * sum_r sum_d S[r,h,d]*rel_msg[r,h,d,k]
        int k0 = d0;
        float o0 = 0.f, o1 = 0.f;
        #pragma unroll
        for (int r = 0; r < 4; ++r) {
            const float* rm = rel_msg + ((size_t)(r * 8 + h)) * 256;
            #pragma unroll
            for (int d2 = 0; d2 < 16; ++d2) {
                float sv = Ssh[w][r * 128 + h * 16 + d2];
                float2 rm2 = *(const float2*)&rm[d2 * 16 + k0];
                o0 = fmaf(sv, rm2.x, o0);
                o1 = fmaf(sv, rm2.y, o1);
            }
        }
        float inv = (den > 0.f) ? 1.f / den : 0.f;
        float2 outv = make_float2(o0 * inv, o1 * inv);
        *(float2*)&aggr[(size_t)dst * 128 + h * 16 + k0] = outv;
    }
}

// ---------------- gelu + Wa proj + skip + LayerNorm ----------------
__global__ __launch_bounds__(128)
void node_out(const float* __restrict__ aggr, const float* __restrict__ x,
              const int* __restrict__ nt, const int* __restrict__ order,
              const float* __restrict__ Wa, const float* __restrict__ ba,
              const float* __restrict__ skip, const float* __restrict__ gamma,
              const float* __restrict__ beta, float* __restrict__ out, int N) {
    __shared__ float hs[16][132];
    __shared__ int gid_s[16], typ_s[16];
    __shared__ float mu_s[16], rs_s[16];
    int o = threadIdx.x;
    int base = blockIdx.x * 16;
    if (o < 16) {
        int n = base + o;
        int g = (n < N) ? order[n] : -1;
        gid_s[o] = g;
        typ_s[o] = (g >= 0) ? nt[g] : 0;
    }
    __syncthreads();
    for (int n = 0; n < 16; ++n) {
        int g = gid_s[n];
        float v = (g >= 0) ? aggr[(size_t)g * 128 + o] : 0.f;
        hs[n][o] = 0.5f * v * (1.f + erff(v * 0.70710678118654752f));  // exact gelu
    }
    __syncthreads();

    int t0 = typ_s[0];
    bool uniform = true;
    for (int n = 1; n < 16; ++n) uniform &= (typ_s[n] == t0);

    float acc[16];
    if (uniform) {
        float bv = ba[t0 * 128 + o];
        for (int n = 0; n < 16; ++n) acc[n] = bv;
        const float* wp = Wa + (size_t)t0 * 16384 + o;
        #pragma unroll 4
        for (int i = 0; i < 128; ++i) {
            float wv = wp[i * 128];
            #pragma unroll
            for (int n = 0; n < 16; ++n) acc[n] = fmaf(hs[n][i], wv, acc[n]);
        }
    } else {
        for (int n = 0; n < 16; ++n) acc[n] = ba[typ_s[n] * 128 + o];
        for (int i = 0; i < 128; ++i) {
            #pragma unroll
            for (int n = 0; n < 16; ++n)
                acc[n] = fmaf(hs[n][i], Wa[(size_t)typ_s[n] * 16384 + i * 128 + o], acc[n]);
        }
    }
    __syncthreads();

    float pre[16];
    for (int n = 0; n < 16; ++n) {
        int g = gid_s[n];
        if (g >= 0) {
            float al = 1.f / (1.f + expf(-skip[typ_s[n]]));
            pre[n] = acc[n] * al + x[(size_t)g * 128 + o] * (1.f - al);
        } else pre[n] = 0.f;
        hs[n][o] = pre[n];
    }
    __syncthreads();

    int rn = o >> 3, j = o & 7;
    float s = 0.f, sq2 = 0.f;
    #pragma unroll
    for (int k2 = 0; k2 < 16; ++k2) {
        float v = hs[rn][j + 8 * k2];
        s += v; sq2 += v * v;
    }
    s += __shfl_xor(s, 1); sq2 += __shfl_xor(sq2, 1);
    s += __shfl_xor(s, 2); sq2 += __shfl_xor(sq2, 2);
    s += __shfl_xor(s, 4); sq2 += __shfl_xor(sq2, 4);
    if (j == 0) {
        float mu = s * (1.f / 128.f);
        float var = sq2 * (1.f / 128.f) - mu * mu;
        mu_s[rn] = mu;
        rs_s[rn] = rsqrtf(fmaxf(var, 0.f) + 1e-5f);
    }
    __syncthreads();

    for (int n = 0; n < 16; ++n) {
        int g = gid_s[n];
        if (g >= 0) {
            int t = typ_s[n];
            out[(size_t)g * 128 + o] =
                (pre[n] - mu_s[n]) * rs_s[n] * gamma[t * 128 + o] + beta[t * 128 + o];
        }
    }
}

extern "C" void kernel_launch(void* const* d_in, const int* in_sizes, int n_in,
                              void* d_out, int out_size, void* d_ws, size_t ws_size,
                              hipStream_t stream) {
    const float* x   = (const float*)d_in[0];
    const int*   nt  = (const int*)d_in[1];
    const int*   ei  = (const int*)d_in[2];
    const int*   et  = (const int*)d_in[3];
    const float* Wk = (const float*)d_in[5];  const float* bk = (const float*)d_in[6];
    const float* Wq = (const float*)d_in[7];  const float* bq = (const float*)d_in[8];
    const float* Wv = (const float*)d_in[9];  const float* bv = (const float*)d_in[10];
    const float* Wa = (const float*)d_in[11]; const float* ba = (const float*)d_in[12];
    const float* rel_pri = (const float*)d_in[13];
    const float* rel_att = (const float*)d_in[14];
    const float* rel_msg = (const float*)d_in[15];
    const float* skip    = (const float*)d_in[16];
    const float* gamma   = (const float*)d_in[17];
    const float* beta    = (const float*)d_in[18];

    const int N = in_sizes[0] / 128;
    const int E = in_sizes[3];
    const int NB = (N + 511) / 512;

    float* ws = (float*)d_ws;
    float* Kb = ws;
    float* Qb = Kb + (size_t)N * 128;
    float* Vb = Qb + (size_t)N * 128;
    float* aggr = Vb + (size_t)N * 128;              // N*128
    int* order  = (int*)(aggr + (size_t)N * 128);    // N
    int* cnt    = order + N;                         // 4
    int* cursorT = cnt + 4;                          // 4
    int* deg    = cursorT + 4;                       // N
    int* off    = deg + N;                           // N
    int* bsum   = off + N;                           // NB (+pad)
    int* cursorD = bsum + NB + 8;                    // N
    int* elist  = cursorD + N;                       // E

    hipMemsetAsync(cnt, 0, 8 * sizeof(int), stream);
    hipMemsetAsync(deg, 0, (size_t)N * sizeof(int), stream);
    hipMemsetAsync(cursorD, 0, (size_t)N * sizeof(int), stream);

    // type sort (for weight-uniform projection blocks)
    hist_k<<<(N + 255) / 256, 256, 0, stream>>>(nt, cnt, N);
    scan_types_k<<<1, 64, 0, stream>>>(cnt, cursorT);
    scatter_types_k<<<(N + 255) / 256, 256, 0, stream>>>(nt, cursorT, order, N);

    // dst-CSR
    deg_k<<<(E + 255) / 256, 256, 0, stream>>>(ei, deg, E);
    scan1_k<<<NB, 512, 0, stream>>>(deg, off, bsum, N);
    scan2_k<<<1, 64, 0, stream>>>(bsum, NB);
    scan3_k<<<NB, 512, 0, stream>>>(off, bsum, N);
    scatter_edges_k<<<(E + 255) / 256, 256, 0, stream>>>(ei, et, off, cursorD, elist, E);

    int nb16 = (N + 15) / 16;
    proj_kqv<<<nb16, 128, 0, stream>>>(x, nt, order, Wk, bk, Wq, bq, Wv, bv, Kb, Qb, Vb, N);
    edge_fused<<<(N + 3) / 4, 256, 0, stream>>>(Kb, Qb, Vb, off, elist, rel_att, rel_msg,
                                                rel_pri, aggr, N, E);
    node_out<<<nb16, 128, 0, stream>>>(aggr, x, nt, order, Wa, ba, skip, gamma, beta,
                                       (float*)d_out, N);
}

// Round 3
// 2124.136 us; speedup vs baseline: 1.2539x; 1.0726x over previous
//
#include <hip/hip_runtime.h>
#include <math.h>

#define D_DIM 128

// ---------------- type sort (counting sort, T=4) ----------------
__global__ void hist_k(const int* __restrict__ nt, int* __restrict__ cnt, int N) {
    int i = blockIdx.x * 256 + threadIdx.x;
    if (i < N) atomicAdd(&cnt[nt[i]], 1);
}
__global__ void scan_types_k(const int* __restrict__ cnt, int* __restrict__ cursor) {
    if (threadIdx.x == 0) {
        int s = 0;
        for (int t = 0; t < 4; ++t) { cursor[t] = s; s += cnt[t]; }
    }
}
__global__ void scatter_types_k(const int* __restrict__ nt, int* __restrict__ cursor,
                                int* __restrict__ order, int N) {
    int i = blockIdx.x * 256 + threadIdx.x;
    if (i < N) {
        int p = atomicAdd(&cursor[nt[i]], 1);
        order[p] = i;
    }
}

// ---------------- dst-CSR build ----------------
__global__ void deg_k(const int* __restrict__ ei, int* __restrict__ deg, int E) {
    int e = blockIdx.x * 256 + threadIdx.x;
    if (e < E) atomicAdd(&deg[ei[E + e]], 1);
}
__global__ void scan1_k(const int* __restrict__ deg, int* __restrict__ excl,
                        int* __restrict__ bsum, int N) {
    __shared__ int s[512];
    int i = blockIdx.x * 512 + threadIdx.x;
    int v = (i < N) ? deg[i] : 0;
    s[threadIdx.x] = v;
    __syncthreads();
    for (int off = 1; off < 512; off <<= 1) {
        int t = (threadIdx.x >= off) ? s[threadIdx.x - off] : 0;
        __syncthreads();
        s[threadIdx.x] += t;
        __syncthreads();
    }
    if (i < N) excl[i] = s[threadIdx.x] - v;
    if (threadIdx.x == 511) bsum[blockIdx.x] = s[511];
}
__global__ void scan2_k(int* __restrict__ bsum, int nb) {
    if (threadIdx.x == 0) {
        int run = 0;
        for (int b = 0; b < nb; ++b) { int t = bsum[b]; bsum[b] = run; run += t; }
    }
}
__global__ void scan3_k(int* __restrict__ excl, const int* __restrict__ bsum, int N) {
    int i = blockIdx.x * 512 + threadIdx.x;
    if (i < N) excl[i] += bsum[blockIdx.x];
}
__global__ void scatter_edges_k(const int* __restrict__ ei, const int* __restrict__ et,
                                const int* __restrict__ off, int* __restrict__ cursor,
                                int* __restrict__ elist, int E) {
    int e = blockIdx.x * 256 + threadIdx.x;
    if (e < E) {
        int dst = ei[E + e];
        int p = off[dst] + atomicAdd(&cursor[dst], 1);
        elist[p] = (ei[e] << 2) | et[e];
    }
}

// ---------------- K/Q/V projections: 16 nodes per 128-thread block ----------------
__global__ __launch_bounds__(128)
void proj_kqv(const float* __restrict__ x, const int* __restrict__ nt,
              const int* __restrict__ order,
              const float* __restrict__ Wk, const float* __restrict__ bk,
              const float* __restrict__ Wq, const float* __restrict__ bq,
              const float* __restrict__ Wv, const float* __restrict__ bv,
              float* __restrict__ K, float* __restrict__ Q, float* __restrict__ V,
              int N) {
    __shared__ float xs[16][128];
    __shared__ int gid_s[16], typ_s[16];
    int o = threadIdx.x;
    int base = blockIdx.x * 16;
    if (o < 16) {
        int n = base + o;
        int g = (n < N) ? order[n] : -1;
        gid_s[o] = g;
        typ_s[o] = (g >= 0) ? nt[g] : 0;
    }
    __syncthreads();
    for (int n = 0; n < 16; ++n) {
        int g = gid_s[n];
        xs[n][o] = (g >= 0) ? x[(size_t)g * D_DIM + o] : 0.f;
    }
    __syncthreads();

    int t0 = typ_s[0];
    bool uniform = true;
    for (int n = 1; n < 16; ++n) uniform &= (typ_s[n] == t0);

    float ak[16], aq[16], av[16];
    if (uniform) {
        float bkv = bk[t0 * 128 + o], bqv = bq[t0 * 128 + o], bvv = bv[t0 * 128 + o];
        for (int n = 0; n < 16; ++n) { ak[n] = bkv; aq[n] = bqv; av[n] = bvv; }
        const float* wkp = Wk + (size_t)t0 * 16384 + o;
        const float* wqp = Wq + (size_t)t0 * 16384 + o;
        const float* wvp = Wv + (size_t)t0 * 16384 + o;
        #pragma unroll 1
        for (int i = 0; i < 128; i += 4) {
            float wkv[4], wqv[4], wvv[4];
            #pragma unroll
            for (int u = 0; u < 4; ++u) {
                wkv[u] = wkp[(i + u) * 128];
                wqv[u] = wqp[(i + u) * 128];
                wvv[u] = wvp[(i + u) * 128];
            }
            #pragma unroll
            for (int n = 0; n < 16; ++n) {
                float4 xv = *(const float4*)&xs[n][i];
                ak[n] = fmaf(xv.x, wkv[0], ak[n]); ak[n] = fmaf(xv.y, wkv[1], ak[n]);
                ak[n] = fmaf(xv.z, wkv[2], ak[n]); ak[n] = fmaf(xv.w, wkv[3], ak[n]);
                aq[n] = fmaf(xv.x, wqv[0], aq[n]); aq[n] = fmaf(xv.y, wqv[1], aq[n]);
                aq[n] = fmaf(xv.z, wqv[2], aq[n]); aq[n] = fmaf(xv.w, wqv[3], aq[n]);
                av[n] = fmaf(xv.x, wvv[0], av[n]); av[n] = fmaf(xv.y, wvv[1], av[n]);
                av[n] = fmaf(xv.z, wvv[2], av[n]); av[n] = fmaf(xv.w, wvv[3], av[n]);
            }
        }
    } else {
        for (int n = 0; n < 16; ++n) {
            int t = typ_s[n];
            ak[n] = bk[t * 128 + o]; aq[n] = bq[t * 128 + o]; av[n] = bv[t * 128 + o];
        }
        for (int i = 0; i < 128; ++i) {
            #pragma unroll
            for (int n = 0; n < 16; ++n) {
                int t = typ_s[n];
                float xv = xs[n][i];
                ak[n] = fmaf(xv, Wk[(size_t)t * 16384 + i * 128 + o], ak[n]);
                aq[n] = fmaf(xv, Wq[(size_t)t * 16384 + i * 128 + o], aq[n]);
                av[n] = fmaf(xv, Wv[(size_t)t * 16384 + i * 128 + o], av[n]);
            }
        }
    }
    for (int n = 0; n < 16; ++n) {
        int g = gid_s[n];
        if (g >= 0) {
            K[(size_t)g * D_DIM + o] = ak[n];
            Q[(size_t)g * D_DIM + o] = aq[n];
            V[(size_t)g * D_DIM + o] = av[n];
        }
    }
}

// ---------------- fused per-dst edge kernel: one wave per dst, LDS-free ----------------
// lane l: head h = l>>3, j = l&7, owns dims d0=2j, d0+1 of head h
__global__ __launch_bounds__(256)
void edge_fused(const float* __restrict__ K, const float* __restrict__ Q,
                const float* __restrict__ V,
                const int* __restrict__ off, const int* __restrict__ elist,
                const float* __restrict__ rel_att, const float* __restrict__ rel_msg,
                const float* __restrict__ rel_pri,
                float* __restrict__ aggr, int N, int E) {
    int w = threadIdx.x >> 6, l = threadIdx.x & 63;
    int dst = blockIdx.x * 4 + w;
    if (dst >= N) return;
    int h = l >> 3, j = l & 7;
    int hb = h << 3;
    int d0 = 2 * j;

    // Q row broadcast via shuffles: qk[k] = Q[dst, h*16+k]
    float2 qv = *(const float2*)&Q[(size_t)dst * 128 + 2 * l];
    float qk[16];
    #pragma unroll
    for (int kk = 0; kk < 8; ++kk) {
        qk[2 * kk]     = __shfl(qv.x, hb + kk);
        qk[2 * kk + 1] = __shfl(qv.y, hb + kk);
    }

    // qrel[r] for columns d0,d0+1, pre-scaled by pri/sqrt(DK)
    float qr0[4], qr1[4];
    #pragma unroll
    for (int r = 0; r < 4; ++r) {
        const float* ra = rel_att + ((size_t)(r * 8 + h)) * 256;
        float a0 = 0.f, a1 = 0.f;
        #pragma unroll
        for (int k4 = 0; k4 < 4; ++k4) {
            float4 r0 = *(const float4*)&ra[d0 * 16 + 4 * k4];
            float4 r1 = *(const float4*)&ra[(d0 + 1) * 16 + 4 * k4];
            a0 += qk[4*k4]*r0.x + qk[4*k4+1]*r0.y + qk[4*k4+2]*r0.z + qk[4*k4+3]*r0.w;
            a1 += qk[4*k4]*r1.x + qk[4*k4+1]*r1.y + qk[4*k4+2]*r1.z + qk[4*k4+3]*r1.w;
        }
        float sc = rel_pri[r * 8 + h] * 0.25f;
        qr0[r] = a0 * sc; qr1[r] = a1 * sc;
    }

    float S0[4] = {0.f, 0.f, 0.f, 0.f};
    float S1[4] = {0.f, 0.f, 0.f, 0.f};
    float den = 0.f;

    int e0 = off[dst];
    int e1 = (dst == N - 1) ? E : off[dst + 1];

    for (int base = e0; base < e1; base += 64) {
        int cnt = min(64, e1 - base);
        int pk_l = elist[min(base + l, e1 - 1)];  // one coalesced load covers 64 edges
        for (int s = 0; s < cnt; s += 4) {
            int i1 = min(s + 1, cnt - 1), i2 = min(s + 2, cnt - 1), i3 = min(s + 3, cnt - 1);
            int pk0 = __shfl(pk_l, s);
            int pk1 = __shfl(pk_l, i1);
            int pk2 = __shfl(pk_l, i2);
            int pk3 = __shfl(pk_l, i3);
            // issue all 8 gathers before any use
            float2 kv0 = *(const float2*)&K[(size_t)(pk0 >> 2) * 128 + 2 * l];
            float2 kv1 = *(const float2*)&K[(size_t)(pk1 >> 2) * 128 + 2 * l];
            float2 kv2 = *(const float2*)&K[(size_t)(pk2 >> 2) * 128 + 2 * l];
            float2 kv3 = *(const float2*)&K[(size_t)(pk3 >> 2) * 128 + 2 * l];
            float2 vv0 = *(const float2*)&V[(size_t)(pk0 >> 2) * 128 + 2 * l];
            float2 vv1 = *(const float2*)&V[(size_t)(pk1 >> 2) * 128 + 2 * l];
            float2 vv2 = *(const float2*)&V[(size_t)(pk2 >> 2) * 128 + 2 * l];
            float2 vv3 = *(const float2*)&V[(size_t)(pk3 >> 2) * 128 + 2 * l];
            int r0 = pk0 & 3, r1 = pk1 & 3, r2 = pk2 & 3, r3 = pk3 & 3;

            float a0 = r0==0?qr0[0]:r0==1?qr0[1]:r0==2?qr0[2]:qr0[3];
            float b0 = r0==0?qr1[0]:r0==1?qr1[1]:r0==2?qr1[2]:qr1[3];
            float a1 = r1==0?qr0[0]:r1==1?qr0[1]:r1==2?qr0[2]:qr0[3];
            float b1 = r1==0?qr1[0]:r1==1?qr1[1]:r1==2?qr1[2]:qr1[3];
            float a2 = r2==0?qr0[0]:r2==1?qr0[1]:r2==2?qr0[2]:qr0[3];
            float b2 = r2==0?qr1[0]:r2==1?qr1[1]:r2==2?qr1[2]:qr1[3];
            float a3 = r3==0?qr0[0]:r3==1?qr0[1]:r3==2?qr0[2]:qr0[3];
            float b3 = r3==0?qr1[0]:r3==1?qr1[1]:r3==2?qr1[2]:qr1[3];

            float dt0 = kv0.x * a0 + kv0.y * b0;
            float dt1 = kv1.x * a1 + kv1.y * b1;
            float dt2 = kv2.x * a2 + kv2.y * b2;
            float dt3 = kv3.x * a3 + kv3.y * b3;
            // 4 independent 8-lane reductions
            dt0 += __shfl_xor(dt0, 1); dt1 += __shfl_xor(dt1, 1);
            dt2 += __shfl_xor(dt2, 1); dt3 += __shfl_xor(dt3, 1);
            dt0 += __shfl_xor(dt0, 2); dt1 += __shfl_xor(dt1, 2);
            dt2 += __shfl_xor(dt2, 2); dt3 += __shfl_xor(dt3, 2);
            dt0 += __shfl_xor(dt0, 4); dt1 += __shfl_xor(dt1, 4);
            dt2 += __shfl_xor(dt2, 4); dt3 += __shfl_xor(dt3, 4);

            float w0v = __expf(dt0);
            float w1v = (s + 1 < cnt) ? __expf(dt1) : 0.f;
            float w2v = (s + 2 < cnt) ? __expf(dt2) : 0.f;
            float w3v = (s + 3 < cnt) ? __expf(dt3) : 0.f;
            den += w0v + w1v + w2v + w3v;

            #pragma unroll
            for (int r = 0; r < 4; ++r) {
                float m0 = (r0 == r) ? w0v : 0.f;
                float m1 = (r1 == r) ? w1v : 0.f;
                float m2 = (r2 == r) ? w2v : 0.f;
                float m3 = (r3 == r) ? w3v : 0.f;
                S0[r] = fmaf(m0, vv0.x, S0[r]); S1[r] = fmaf(m0, vv0.y, S1[r]);
                S0[r] = fmaf(m1, vv1.x, S0[r]); S1[r] = fmaf(m1, vv1.y, S1[r]);
                S0[r] = fmaf(m2, vv2.x, S0[r]); S1[r] = fmaf(m2, vv2.y, S1[r]);
                S0[r] = fmaf(m3, vv3.x, S0[r]); S1[r] = fmaf(m3, vv3.y, S1[r]);
            }
        }
    }

    // epilogue: out[h, d0..d0+1] = (1/den) * sum_r sum_d S[r,h,d]*rel_msg[r,h,d,k]
    float o0 = 0.f, o1 = 0.f;
    #pragma unroll
    for (int r = 0; r < 4; ++r) {
        const float* rm = rel_msg + ((size_t)(r * 8 + h)) * 256;
        #pragma unroll
        for (int jj = 0; jj < 8; ++jj) {
            float s0 = __shfl(S0[r], hb + jj);   // S[r,h,2jj]
            float s1 = __shfl(S1[r], hb + jj);   // S[r,h,2jj+1]
            float2 rm0 = *(const float2*)&rm[(2 * jj) * 16 + d0];
            float2 rm1 = *(const float2*)&rm[(2 * jj + 1) * 16 + d0];
            o0 += s0 * rm0.x + s1 * rm1.x;
            o1 += s0 * rm0.y + s1 * rm1.y;
        }
    }
    float inv = (den > 0.f) ? 1.f / den : 0.f;
    *(float2*)&aggr[(size_t)dst * 128 + h * 16 + d0] = make_float2(o0 * inv, o1 * inv);
}

// ---------------- gelu + Wa proj + skip + LayerNorm ----------------
__global__ __launch_bounds__(128)
void node_out(const float* __restrict__ aggr, const float* __restrict__ x,
              const int* __restrict__ nt, const int* __restrict__ order,
              const float* __restrict__ Wa, const float* __restrict__ ba,
              const float* __restrict__ skip, const float* __restrict__ gamma,
              const float* __restrict__ beta, float* __restrict__ out, int N) {
    __shared__ float hs[16][128];
    __shared__ int gid_s[16], typ_s[16];
    __shared__ float mu_s[16], rs_s[16];
    int o = threadIdx.x;
    int base = blockIdx.x * 16;
    if (o < 16) {
        int n = base + o;
        int g = (n < N) ? order[n] : -1;
        gid_s[o] = g;
        typ_s[o] = (g >= 0) ? nt[g] : 0;
    }
    __syncthreads();
    for (int n = 0; n < 16; ++n) {
        int g = gid_s[n];
        float v = (g >= 0) ? aggr[(size_t)g * 128 + o] : 0.f;
        hs[n][o] = 0.5f * v * (1.f + erff(v * 0.70710678118654752f));  // exact gelu
    }
    __syncthreads();

    int t0 = typ_s[0];
    bool uniform = true;
    for (int n = 1; n < 16; ++n) uniform &= (typ_s[n] == t0);

    float acc[16];
    if (uniform) {
        float bv = ba[t0 * 128 + o];
        for (int n = 0; n < 16; ++n) acc[n] = bv;
        const float* wp = Wa + (size_t)t0 * 16384 + o;
        #pragma unroll 1
        for (int i = 0; i < 128; i += 4) {
            float wv[4];
            #pragma unroll
            for (int u = 0; u < 4; ++u) wv[u] = wp[(i + u) * 128];
            #pragma unroll
            for (int n = 0; n < 16; ++n) {
                float4 hv = *(const float4*)&hs[n][i];
                acc[n] = fmaf(hv.x, wv[0], acc[n]); acc[n] = fmaf(hv.y, wv[1], acc[n]);
                acc[n] = fmaf(hv.z, wv[2], acc[n]); acc[n] = fmaf(hv.w, wv[3], acc[n]);
            }
        }
    } else {
        for (int n = 0; n < 16; ++n) acc[n] = ba[typ_s[n] * 128 + o];
        for (int i = 0; i < 128; ++i) {
            #pragma unroll
            for (int n = 0; n < 16; ++n)
                acc[n] = fmaf(hs[n][i], Wa[(size_t)typ_s[n] * 16384 + i * 128 + o], acc[n]);
        }
    }
    __syncthreads();

    float pre[16];
    for (int n = 0; n < 16; ++n) {
        int g = gid_s[n];
        if (g >= 0) {
            float al = 1.f / (1.f + expf(-skip[typ_s[n]]));
            pre[n] = acc[n] * al + x[(size_t)g * 128 + o] * (1.f - al);
        } else pre[n] = 0.f;
        hs[n][o] = pre[n];
    }
    __syncthreads();

    int rn = o >> 3, jj = o & 7;
    float s = 0.f, sq2 = 0.f;
    #pragma unroll
    for (int k2 = 0; k2 < 16; ++k2) {
        float v = hs[rn][jj + 8 * k2];
        s += v; sq2 += v * v;
    }
    s += __shfl_xor(s, 1); sq2 += __shfl_xor(sq2, 1);
    s += __shfl_xor(s, 2); sq2 += __shfl_xor(sq2, 2);
    s += __shfl_xor(s, 4); sq2 += __shfl_xor(sq2, 4);
    if (jj == 0) {
        float mu = s * (1.f / 128.f);
        float var = sq2 * (1.f / 128.f) - mu * mu;
        mu_s[rn] = mu;
        rs_s[rn] = rsqrtf(fmaxf(var, 0.f) + 1e-5f);
    }
    __syncthreads();

    for (int n = 0; n < 16; ++n) {
        int g = gid_s[n];
        if (g >= 0) {
            int t = typ_s[n];
            out[(size_t)g * 128 + o] =
                (pre[n] - mu_s[n]) * rs_s[n] * gamma[t * 128 + o] + beta[t * 128 + o];
        }
    }
}

extern "C" void kernel_launch(void* const* d_in, const int* in_sizes, int n_in,
                              void* d_out, int out_size, void* d_ws, size_t ws_size,
                              hipStream_t stream) {
    const float* x   = (const float*)d_in[0];
    const int*   nt  = (const int*)d_in[1];
    const int*   ei  = (const int*)d_in[2];
    const int*   et  = (const int*)d_in[3];
    const float* Wk = (const float*)d_in[5];  const float* bk = (const float*)d_in[6];
    const float* Wq = (const float*)d_in[7];  const float* bq = (const float*)d_in[8];
    const float* Wv = (const float*)d_in[9];  const float* bv = (const float*)d_in[10];
    const float* Wa = (const float*)d_in[11]; const float* ba = (const float*)d_in[12];
    const float* rel_pri = (const float*)d_in[13];
    const float* rel_att = (const float*)d_in[14];
    const float* rel_msg = (const float*)d_in[15];
    const float* skip    = (const float*)d_in[16];
    const float* gamma   = (const float*)d_in[17];
    const float* beta    = (const float*)d_in[18];

    const int N = in_sizes[0] / 128;
    const int E = in_sizes[3];
    const int NB = (N + 511) / 512;

    float* ws = (float*)d_ws;
    float* Kb = ws;
    float* Qb = Kb + (size_t)N * 128;
    float* Vb = Qb + (size_t)N * 128;
    float* aggr = Vb + (size_t)N * 128;              // N*128
    int* order  = (int*)(aggr + (size_t)N * 128);    // N
    int* cnt    = order + N;                         // 4
    int* cursorT = cnt + 4;                          // 4
    int* deg    = cursorT + 4;                       // N
    int* off    = deg + N;                           // N
    int* bsum   = off + N;                           // NB (+pad)
    int* cursorD = bsum + NB + 8;                    // N
    int* elist  = cursorD + N;                       // E

    hipMemsetAsync(cnt, 0, 8 * sizeof(int), stream);
    hipMemsetAsync(deg, 0, (size_t)N * sizeof(int), stream);
    hipMemsetAsync(cursorD, 0, (size_t)N * sizeof(int), stream);

    // type sort (for weight-uniform projection blocks)
    hist_k<<<(N + 255) / 256, 256, 0, stream>>>(nt, cnt, N);
    scan_types_k<<<1, 64, 0, stream>>>(cnt, cursorT);
    scatter_types_k<<<(N + 255) / 256, 256, 0, stream>>>(nt, cursorT, order, N);

    // dst-CSR
    deg_k<<<(E + 255) / 256, 256, 0, stream>>>(ei, deg, E);
    scan1_k<<<NB, 512, 0, stream>>>(deg, off, bsum, N);
    scan2_k<<<1, 64, 0, stream>>>(bsum, NB);
    scan3_k<<<NB, 512, 0, stream>>>(off, bsum, N);
    scatter_edges_k<<<(E + 255) / 256, 256, 0, stream>>>(ei, et, off, cursorD, elist, E);

    int nb16 = (N + 15) / 16;
    proj_kqv<<<nb16, 128, 0, stream>>>(x, nt, order, Wk, bk, Wq, bq, Wv, bv, Kb, Qb, Vb, N);
    edge_fused<<<(N + 3) / 4, 256, 0, stream>>>(Kb, Qb, Vb, off, elist, rel_att, rel_msg,
                                                rel_pri, aggr, N, E);
    node_out<<<nb16, 128, 0, stream>>>(aggr, x, nt, order, Wa, ba, skip, gamma, beta,
                                       (float*)d_out, N);
}